// Round 2
// baseline (1549.314 us; speedup 1.0000x reference)
//
#include <hip/hip_runtime.h>

// Problem constants
#define NB 32
#define NS 2048
#define ND 512
#define NFF 512
#define SCALE 0.044194173824159216f
#define CPB 64
#define ROWS 32
#define GRID 2048

// Workspace float offsets
#define OFF_XWP 0
#define OFF_XW  1048576
#define OFF_KWS 1064960
#define OFF_WQS 1081344
#define OFF_CB2 1097728
#define OFF_XT  1097760
#define OFF_ST  1114144
#define OFF_SW  1114176
#define OFF_BAR 1114200   // 8 x unsigned barrier counters

__device__ __forceinline__ float dot4(float4 a, float4 b) {
    return a.x * b.x + a.y * b.y + a.z * b.z + a.w * b.w;
}

__device__ __forceinline__ float wave_reduce(float p) {
#pragma unroll
    for (int m = 1; m < 64; m <<= 1) p += __shfl_xor(p, m, 64);
    return p;
}

// Grid-wide barrier: all GRID blocks are co-resident (launch_bounds(256,8)
// -> 8 blocks/CU x 256 CUs = 2048). One-shot counter per barrier instance,
// zeroed by hipMemsetAsync before launch. __threadfence() provides the
// agent-scope release/acquire (L2 writeback/invalidate across XCDs).
// Bounded spin: a logic bug fails correctness visibly instead of hanging.
__device__ __forceinline__ void grid_barrier(unsigned* bar) {
    __syncthreads();
    if (threadIdx.x == 0) {
        __threadfence();  // release: publish this block's writes
        __hip_atomic_fetch_add(bar, 1u, __ATOMIC_RELAXED, __HIP_MEMORY_SCOPE_AGENT);
        long spin = 0;
        while (__hip_atomic_load(bar, __ATOMIC_RELAXED, __HIP_MEMORY_SCOPE_AGENT) < GRID) {
            __builtin_amdgcn_s_sleep(2);
            if (++spin > (1L << 18)) break;
        }
        __threadfence();  // acquire: invalidate stale L1/L2 lines
    }
    __syncthreads();
}

// ---- P1: xwp[blk][d] = sum_{s in chunk} Wt[s]*x[b,s,d]; zero xt/st --------
__device__ void d_pass1(int blk, const float* __restrict__ x,
                        const float* __restrict__ Wt,
                        float* __restrict__ xwp, float* __restrict__ xt,
                        float* __restrict__ st, float* sm) {
    const int b = blk >> 6;
    const int chunk = blk & 63;
    const int s0 = chunk * ROWS;
    const int t = threadIdx.x;
    const int col = t & 127;
    const int half = t >> 7;

    if (blk < NB) {  // zero the atomic accumulators for batch blk
        xt[blk * ND + t] = 0.f;
        xt[blk * ND + 256 + t] = 0.f;
        if (t == 0) st[blk] = 0.f;
    }

    const float4* xb = (const float4*)(x + (size_t)b * NS * ND);
    float4 acc = make_float4(0.f, 0.f, 0.f, 0.f);
#pragma unroll 4
    for (int i = 0; i < 16; i++) {
        int s = s0 + half + 2 * i;
        float w = Wt[s];
        float4 v = xb[(size_t)s * 128 + col];
        acc.x += w * v.x; acc.y += w * v.y; acc.z += w * v.z; acc.w += w * v.w;
    }
    float4* red = (float4*)sm;
    if (half == 1) red[col] = acc;
    __syncthreads();
    if (half == 0) {
        float4 o = red[col];
        o.x += acc.x; o.y += acc.y; o.z += acc.z; o.w += acc.w;
        ((float4*)xwp)[(size_t)blk * 128 + col] = o;
    }
}

// ---- P2: xw[b][d] = sum_c xwp[b,c][d]; block 0 computes sw=sum(Wt) --------
__device__ void d_xwred(int blk, const float* __restrict__ xwp,
                        const float* __restrict__ Wt,
                        float* __restrict__ xw, float* __restrict__ sw) {
    const int b = blk >> 1;
    const int d0 = (blk & 1) * 256;
    const int t = threadIdx.x;
    const float* p = xwp + (size_t)b * CPB * ND + d0 + t;
    float a = 0.f;
#pragma unroll 8
    for (int c = 0; c < CPB; c++) a += p[(size_t)c * ND];
    xw[b * ND + d0 + t] = a;
    if (blk == 0 && t < 64) {
        float s = 0.f;
#pragma unroll
        for (int i = 0; i < 32; i++) s += Wt[t + 64 * i];
        s = wave_reduce(s);
        if (t == 0) sw[0] = s;
    }
}

// ---- P3: kwS[b,f] = SCALE*(Wk[f,:].xw[b,:] + bk[f]*sw), 8 f per block -----
__device__ void d_kw(int blk, const float* __restrict__ xw,
                     const float* __restrict__ Wk, const float* __restrict__ bk,
                     const float* __restrict__ sw, float* __restrict__ kwS) {
    const int b = blk >> 6;
    const int t = threadIdx.x;
    const int wv = t >> 6;
    const int lane = t & 63;
    const int f = (blk & 63) * 8 + wv * 2;
    const float4* xw4 = (const float4*)(xw + b * ND);
    const float4 xa = xw4[lane];
    const float4 xc = xw4[64 + lane];
    const float sws = sw[0];
    const float4* w0p = (const float4*)(Wk + (size_t)f * ND);
    const float4* w1p = (const float4*)(Wk + (size_t)(f + 1) * ND);
    float p0 = dot4(xa, w0p[lane]) + dot4(xc, w0p[64 + lane]);
    float p1 = dot4(xa, w1p[lane]) + dot4(xc, w1p[64 + lane]);
#pragma unroll
    for (int m = 1; m < 64; m <<= 1) {
        p0 += __shfl_xor(p0, m, 64);
        p1 += __shfl_xor(p1, m, 64);
    }
    if (lane == 0) {
        kwS[b * NFF + f]     = SCALE * (p0 + bk[f] * sws);
        kwS[b * NFF + f + 1] = SCALE * (p1 + bk[f + 1] * sws);
    }
}

// ---- P4: wqs[b,d] = sum_f kwS[b,f]*Wq[f,d]; cb2[b] = kwS.bq + bt ----------
__device__ void d_wqs(int blk, const float* __restrict__ kwS,
                      const float* __restrict__ Wq, const float* __restrict__ bq,
                      const float* __restrict__ bt, float* __restrict__ wqs,
                      float* __restrict__ cb2, float* sm) {
    const int b = blk >> 1;
    const int d0 = (blk & 1) * 256;
    const int t = threadIdx.x;
    float* sk = sm;        // 512
    float* rd = sm + 512;  // 256
    sk[t] = kwS[b * NFF + t];
    sk[256 + t] = kwS[b * NFF + 256 + t];
    __syncthreads();
    const float* wp = Wq + d0 + t;
    float a0 = 0.f, a1 = 0.f, a2 = 0.f, a3 = 0.f;
#pragma unroll 4
    for (int f = 0; f < NFF; f += 4) {
        a0 += sk[f]     * wp[(size_t)f * ND];
        a1 += sk[f + 1] * wp[(size_t)(f + 1) * ND];
        a2 += sk[f + 2] * wp[(size_t)(f + 2) * ND];
        a3 += sk[f + 3] * wp[(size_t)(f + 3) * ND];
    }
    wqs[b * ND + d0 + t] = (a0 + a1) + (a2 + a3);
    if ((blk & 1) == 0) {
        rd[t] = sk[t] * bq[t] + sk[256 + t] * bq[256 + t];
        __syncthreads();
        for (int off = 128; off > 0; off >>= 1) {
            if (t < off) rd[t] += rd[t + off];
            __syncthreads();
        }
        if (t == 0) cb2[b] = rd[0] + bt[0];
    }
}

// ---- P5: ta = x.wqs + cb2; xt[b,:] += sum_s ta*x; st[b] += sum ta ---------
// Register-lean: 2-row ILP across the shuffle trees, stays under 64 VGPR.
__device__ void d_pass2(int blk, const float* __restrict__ x,
                        const float* __restrict__ wqs,
                        const float* __restrict__ cb2,
                        float* __restrict__ xt, float* __restrict__ st,
                        float* sm) {
    const int b = blk >> 6;
    const int chunk = blk & 63;
    const int t = threadIdx.x;
    const int wv = t >> 6;
    const int lane = t & 63;
    const float4* xb = (const float4*)(x + (size_t)b * NS * ND);
    const float4* wq4 = (const float4*)(wqs + b * ND);
    const float4 w0 = wq4[lane];
    const float4 w1 = wq4[64 + lane];
    const float c = cb2[b];
    float4 a0 = make_float4(0.f, 0.f, 0.f, 0.f);
    float4 a1 = make_float4(0.f, 0.f, 0.f, 0.f);
    float sta = 0.f;
#pragma unroll
    for (int g = 0; g < 4; g++) {
        int s = chunk * ROWS + wv * 8 + 2 * g;
        float4 u0 = xb[(size_t)s * 128 + lane];
        float4 u1 = xb[(size_t)s * 128 + 64 + lane];
        float4 v0 = xb[(size_t)(s + 1) * 128 + lane];
        float4 v1 = xb[(size_t)(s + 1) * 128 + 64 + lane];
        float pa = dot4(u0, w0) + dot4(u1, w1);
        float pb = dot4(v0, w0) + dot4(v1, w1);
#pragma unroll
        for (int m = 1; m < 64; m <<= 1) {
            pa += __shfl_xor(pa, m, 64);
            pb += __shfl_xor(pb, m, 64);
        }
        float taa = pa + c;
        float tab = pb + c;
        a0.x += taa * u0.x + tab * v0.x; a0.y += taa * u0.y + tab * v0.y;
        a0.z += taa * u0.z + tab * v0.z; a0.w += taa * u0.w + tab * v0.w;
        a1.x += taa * u1.x + tab * v1.x; a1.y += taa * u1.y + tab * v1.y;
        a1.z += taa * u1.z + tab * v1.z; a1.w += taa * u1.w + tab * v1.w;
        sta += taa + tab;
    }
    float4* sh0 = (float4*)sm;              // 4*64 float4
    float4* sh1 = ((float4*)sm) + 256;      // 4*64 float4
    float* sW = sm + 2048;                  // 4
    sh0[wv * 64 + lane] = a0;
    sh1[wv * 64 + lane] = a1;
    if (lane == 0) sW[wv] = sta;
    __syncthreads();
    float* xbt = xt + b * ND;
    if (t < 64) {
        float4 s0 = sh0[t], s1 = sh0[64 + t], s2 = sh0[128 + t], s3 = sh0[192 + t];
        atomicAdd(&xbt[4 * t + 0], s0.x + s1.x + s2.x + s3.x);
        atomicAdd(&xbt[4 * t + 1], s0.y + s1.y + s2.y + s3.y);
        atomicAdd(&xbt[4 * t + 2], s0.z + s1.z + s2.z + s3.z);
        atomicAdd(&xbt[4 * t + 3], s0.w + s1.w + s2.w + s3.w);
    } else if (t < 128) {
        int l = t - 64;
        float4 s0 = sh1[l], s1 = sh1[64 + l], s2 = sh1[128 + l], s3 = sh1[192 + l];
        atomicAdd(&xbt[256 + 4 * l + 0], s0.x + s1.x + s2.x + s3.x);
        atomicAdd(&xbt[256 + 4 * l + 1], s0.y + s1.y + s2.y + s3.y);
        atomicAdd(&xbt[256 + 4 * l + 2], s0.z + s1.z + s2.z + s3.z);
        atomicAdd(&xbt[256 + 4 * l + 3], s0.w + s1.w + s2.w + s3.w);
    } else if (t == 128) {
        atomicAdd(&st[b], sW[0] + sW[1] + sW[2] + sW[3]);
    }
}

// ---- P6: out[b,f] = Wv[f,:].xt[b,:] + bv[f]*st[b], 8 f per block ----------
__device__ void d_out(int blk, const float* __restrict__ xt,
                      const float* __restrict__ st,
                      const float* __restrict__ Wv, const float* __restrict__ bv,
                      float* __restrict__ out) {
    const int b = blk >> 6;
    const int t = threadIdx.x;
    const int wv = t >> 6;
    const int lane = t & 63;
    const int f = (blk & 63) * 8 + wv * 2;
    const float4* xt4 = (const float4*)(xt + b * ND);
    const float4 xa = xt4[lane];
    const float4 xc = xt4[64 + lane];
    const float stb = st[b];
    const float4* w0p = (const float4*)(Wv + (size_t)f * ND);
    const float4* w1p = (const float4*)(Wv + (size_t)(f + 1) * ND);
    float p0 = dot4(xa, w0p[lane]) + dot4(xc, w0p[64 + lane]);
    float p1 = dot4(xa, w1p[lane]) + dot4(xc, w1p[64 + lane]);
#pragma unroll
    for (int m = 1; m < 64; m <<= 1) {
        p0 += __shfl_xor(p0, m, 64);
        p1 += __shfl_xor(p1, m, 64);
    }
    if (lane == 0) {
        out[b * NFF + f]     = p0 + bv[f] * stb;
        out[b * NFF + f + 1] = p1 + bv[f + 1] * stb;
    }
}

// ---- Mono kernel: 6 phases, 5 grid barriers, one launch -------------------
__global__ void __launch_bounds__(256, 8)
k_mono(const float* __restrict__ x, const float* __restrict__ Wq,
       const float* __restrict__ bq, const float* __restrict__ Wk,
       const float* __restrict__ bk, const float* __restrict__ Wv,
       const float* __restrict__ bv, const float* __restrict__ Wt,
       const float* __restrict__ bt, float* __restrict__ out,
       float* __restrict__ ws) {
    __shared__ __align__(16) float sm[2052];
    float* xwp = ws + OFF_XWP;
    float* xw  = ws + OFF_XW;
    float* kwS = ws + OFF_KWS;
    float* wqs = ws + OFF_WQS;
    float* cb2 = ws + OFF_CB2;
    float* xt  = ws + OFF_XT;
    float* st  = ws + OFF_ST;
    float* sw  = ws + OFF_SW;
    unsigned* bar = (unsigned*)(ws + OFF_BAR);
    const int blk = blockIdx.x;

    d_pass1(blk, x, Wt, xwp, xt, st, sm);
    grid_barrier(bar + 0);
    if (blk < 64) d_xwred(blk, xwp, Wt, xw, sw);
    grid_barrier(bar + 1);
    d_kw(blk, xw, Wk, bk, sw, kwS);
    grid_barrier(bar + 2);
    if (blk < 64) d_wqs(blk, kwS, Wq, bq, bt, wqs, cb2, sm);
    grid_barrier(bar + 3);
    d_pass2(blk, x, wqs, cb2, xt, st, sm);
    grid_barrier(bar + 4);
    d_out(blk, xt, st, Wv, bv, out);
}

extern "C" void kernel_launch(void* const* d_in, const int* in_sizes, int n_in,
                              void* d_out, int out_size, void* d_ws, size_t ws_size,
                              hipStream_t stream) {
    const float* x  = (const float*)d_in[0];
    const float* Wq = (const float*)d_in[1];
    const float* bq = (const float*)d_in[2];
    const float* Wk = (const float*)d_in[3];
    const float* bk = (const float*)d_in[4];
    const float* Wv = (const float*)d_in[5];
    const float* bv = (const float*)d_in[6];
    const float* Wt = (const float*)d_in[7];
    const float* bt = (const float*)d_in[8];
    float* out = (float*)d_out;
    float* ws = (float*)d_ws;

    // Zero the 5 (rounded to 8) grid-barrier counters; workspace is poisoned
    // each iteration so this must happen before every launch.
    hipMemsetAsync(ws + OFF_BAR, 0, 8 * sizeof(unsigned), stream);
    k_mono<<<GRID, 256, 0, stream>>>(x, Wq, bq, Wk, bk, Wv, bv, Wt, bt, out, ws);
}

// Round 3
// 816.923 us; speedup vs baseline: 1.8965x; 1.8965x over previous
//
#include <hip/hip_runtime.h>

// Problem constants
#define NB 32
#define NS 2048
#define ND 512
#define NFF 512
#define SCALE 0.044194173824159216f
#define CPB 64
#define ROWS 32
#define GRID 2048

// Workspace float offsets
#define OFF_XWP 0
#define OFF_XW  1048576
#define OFF_KWS 1064960
#define OFF_WQS 1081344
#define OFF_CB2 1097728
#define OFF_XT  1097760
#define OFF_ST  1114144
#define OFF_SW  1114176
#define OFF_SLOT 1114240   // 2048 x u32 arrival slots (128B-aligned)
#define OFF_REL  1116352   // 1 x u32 release word (own cacheline)

__device__ __forceinline__ float dot4(float4 a, float4 b) {
    return a.x * b.x + a.y * b.y + a.z * b.z + a.w * b.w;
}

__device__ __forceinline__ float wave_reduce(float p) {
#pragma unroll
    for (int m = 1; m < 64; m <<= 1) p += __shfl_xor(p, m, 64);
    return p;
}

// Contention-free grid barrier (all GRID blocks co-resident, proven r2):
//  - arrival: each block stores `gen` into its OWN slot (no RMW, no sharing)
//  - block 0 scans slots cooperatively, then publishes `gen` to release word
//  - leaders poll ONLY the release word with s_sleep backoff
// Fences: t0-only release/acquire __threadfence(), same semantics that
// passed correctness in round 2. Bounded spins: bugs fail visibly, no hang.
__device__ __forceinline__ void grid_barrier(unsigned gen, unsigned* slots,
                                             unsigned* release) {
    __syncthreads();
    if (threadIdx.x == 0) {
        __threadfence();  // publish this block's prior writes
        __hip_atomic_store(&slots[blockIdx.x], gen, __ATOMIC_RELAXED,
                           __HIP_MEMORY_SCOPE_AGENT);
    }
    if (blockIdx.x == 0) {
        __shared__ int notdone;
        const int t = threadIdx.x;
        long guard = 0;
        for (;;) {
            if (t == 0) notdone = 0;
            __syncthreads();
            int miss = 0;
#pragma unroll
            for (int i = 0; i < GRID / 256; i++) {
                unsigned v = __hip_atomic_load(&slots[i * 256 + t],
                                               __ATOMIC_RELAXED,
                                               __HIP_MEMORY_SCOPE_AGENT);
                miss |= (v < gen);
            }
            if (miss) notdone = 1;
            __syncthreads();
            if (!notdone) break;
            if (++guard > (1L << 16)) break;  // bail -> visible wrong answer
            __builtin_amdgcn_s_sleep(1);
        }
        if (t == 0) {
            __threadfence();
            __hip_atomic_store(release, gen, __ATOMIC_RELAXED,
                               __HIP_MEMORY_SCOPE_AGENT);
        }
    }
    if (threadIdx.x == 0) {
        long spin = 0;
        while (__hip_atomic_load(release, __ATOMIC_RELAXED,
                                 __HIP_MEMORY_SCOPE_AGENT) < gen) {
            __builtin_amdgcn_s_sleep(8);
            if (++spin > (1L << 18)) break;
        }
        __threadfence();  // acquire: invalidate stale cached lines
    }
    __syncthreads();
}

// ---- P1: xwp[blk][d] = sum_{s in chunk} Wt[s]*x[b,s,d]; zero xt/st --------
__device__ void d_pass1(int blk, const float* __restrict__ x,
                        const float* __restrict__ Wt,
                        float* __restrict__ xwp, float* __restrict__ xt,
                        float* __restrict__ st, float* sm) {
    const int b = blk >> 6;
    const int chunk = blk & 63;
    const int s0 = chunk * ROWS;
    const int t = threadIdx.x;
    const int col = t & 127;
    const int half = t >> 7;

    if (blk < NB) {  // zero the atomic accumulators for batch blk
        xt[blk * ND + t] = 0.f;
        xt[blk * ND + 256 + t] = 0.f;
        if (t == 0) st[blk] = 0.f;
    }

    const float4* xb = (const float4*)(x + (size_t)b * NS * ND);
    float4 acc = make_float4(0.f, 0.f, 0.f, 0.f);
#pragma unroll 4
    for (int i = 0; i < 16; i++) {
        int s = s0 + half + 2 * i;
        float w = Wt[s];
        float4 v = xb[(size_t)s * 128 + col];
        acc.x += w * v.x; acc.y += w * v.y; acc.z += w * v.z; acc.w += w * v.w;
    }
    float4* red = (float4*)sm;
    if (half == 1) red[col] = acc;
    __syncthreads();
    if (half == 0) {
        float4 o = red[col];
        o.x += acc.x; o.y += acc.y; o.z += acc.z; o.w += acc.w;
        ((float4*)xwp)[(size_t)blk * 128 + col] = o;
    }
}

// ---- P2: xw[b][d] = sum_c xwp[b,c][d]; block 0 computes sw=sum(Wt) --------
__device__ void d_xwred(int blk, const float* __restrict__ xwp,
                        const float* __restrict__ Wt,
                        float* __restrict__ xw, float* __restrict__ sw) {
    const int b = blk >> 1;
    const int d0 = (blk & 1) * 256;
    const int t = threadIdx.x;
    const float* p = xwp + (size_t)b * CPB * ND + d0 + t;
    float a = 0.f;
#pragma unroll 8
    for (int c = 0; c < CPB; c++) a += p[(size_t)c * ND];
    xw[b * ND + d0 + t] = a;
    if (blk == 0 && t < 64) {
        float s = 0.f;
#pragma unroll
        for (int i = 0; i < 32; i++) s += Wt[t + 64 * i];
        s = wave_reduce(s);
        if (t == 0) sw[0] = s;
    }
}

// ---- P3: kwS[b,f] = SCALE*(Wk[f,:].xw[b,:] + bk[f]*sw), 8 f per block -----
__device__ void d_kw(int blk, const float* __restrict__ xw,
                     const float* __restrict__ Wk, const float* __restrict__ bk,
                     const float* __restrict__ sw, float* __restrict__ kwS) {
    const int b = blk >> 6;
    const int t = threadIdx.x;
    const int wv = t >> 6;
    const int lane = t & 63;
    const int f = (blk & 63) * 8 + wv * 2;
    const float4* xw4 = (const float4*)(xw + b * ND);
    const float4 xa = xw4[lane];
    const float4 xc = xw4[64 + lane];
    const float sws = sw[0];
    const float4* w0p = (const float4*)(Wk + (size_t)f * ND);
    const float4* w1p = (const float4*)(Wk + (size_t)(f + 1) * ND);
    float p0 = dot4(xa, w0p[lane]) + dot4(xc, w0p[64 + lane]);
    float p1 = dot4(xa, w1p[lane]) + dot4(xc, w1p[64 + lane]);
#pragma unroll
    for (int m = 1; m < 64; m <<= 1) {
        p0 += __shfl_xor(p0, m, 64);
        p1 += __shfl_xor(p1, m, 64);
    }
    if (lane == 0) {
        kwS[b * NFF + f]     = SCALE * (p0 + bk[f] * sws);
        kwS[b * NFF + f + 1] = SCALE * (p1 + bk[f + 1] * sws);
    }
}

// ---- P4: wqs[b,d] = sum_f kwS[b,f]*Wq[f,d]; cb2[b] = kwS.bq + bt ----------
__device__ void d_wqs(int blk, const float* __restrict__ kwS,
                      const float* __restrict__ Wq, const float* __restrict__ bq,
                      const float* __restrict__ bt, float* __restrict__ wqs,
                      float* __restrict__ cb2, float* sm) {
    const int b = blk >> 1;
    const int d0 = (blk & 1) * 256;
    const int t = threadIdx.x;
    float* sk = sm;        // 512
    float* rd = sm + 512;  // 256
    sk[t] = kwS[b * NFF + t];
    sk[256 + t] = kwS[b * NFF + 256 + t];
    __syncthreads();
    const float* wp = Wq + d0 + t;
    float a0 = 0.f, a1 = 0.f, a2 = 0.f, a3 = 0.f;
#pragma unroll 4
    for (int f = 0; f < NFF; f += 4) {
        a0 += sk[f]     * wp[(size_t)f * ND];
        a1 += sk[f + 1] * wp[(size_t)(f + 1) * ND];
        a2 += sk[f + 2] * wp[(size_t)(f + 2) * ND];
        a3 += sk[f + 3] * wp[(size_t)(f + 3) * ND];
    }
    wqs[b * ND + d0 + t] = (a0 + a1) + (a2 + a3);
    if ((blk & 1) == 0) {
        rd[t] = sk[t] * bq[t] + sk[256 + t] * bq[256 + t];
        __syncthreads();
        for (int off = 128; off > 0; off >>= 1) {
            if (t < off) rd[t] += rd[t + off];
            __syncthreads();
        }
        if (t == 0) cb2[b] = rd[0] + bt[0];
    }
}

// ---- P5: ta = x.wqs + cb2; xt[b,:] += sum_s ta*x; st[b] += sum ta ---------
__device__ void d_pass2(int blk, const float* __restrict__ x,
                        const float* __restrict__ wqs,
                        const float* __restrict__ cb2,
                        float* __restrict__ xt, float* __restrict__ st,
                        float* sm) {
    const int b = blk >> 6;
    const int chunk = blk & 63;
    const int t = threadIdx.x;
    const int wv = t >> 6;
    const int lane = t & 63;
    const float4* xb = (const float4*)(x + (size_t)b * NS * ND);
    const float4* wq4 = (const float4*)(wqs + b * ND);
    const float4 w0 = wq4[lane];
    const float4 w1 = wq4[64 + lane];
    const float c = cb2[b];
    float4 a0 = make_float4(0.f, 0.f, 0.f, 0.f);
    float4 a1 = make_float4(0.f, 0.f, 0.f, 0.f);
    float sta = 0.f;
#pragma unroll
    for (int g = 0; g < 4; g++) {
        int s = chunk * ROWS + wv * 8 + 2 * g;
        float4 u0 = xb[(size_t)s * 128 + lane];
        float4 u1 = xb[(size_t)s * 128 + 64 + lane];
        float4 v0 = xb[(size_t)(s + 1) * 128 + lane];
        float4 v1 = xb[(size_t)(s + 1) * 128 + 64 + lane];
        float pa = dot4(u0, w0) + dot4(u1, w1);
        float pb = dot4(v0, w0) + dot4(v1, w1);
#pragma unroll
        for (int m = 1; m < 64; m <<= 1) {
            pa += __shfl_xor(pa, m, 64);
            pb += __shfl_xor(pb, m, 64);
        }
        float taa = pa + c;
        float tab = pb + c;
        a0.x += taa * u0.x + tab * v0.x; a0.y += taa * u0.y + tab * v0.y;
        a0.z += taa * u0.z + tab * v0.z; a0.w += taa * u0.w + tab * v0.w;
        a1.x += taa * u1.x + tab * v1.x; a1.y += taa * u1.y + tab * v1.y;
        a1.z += taa * u1.z + tab * v1.z; a1.w += taa * u1.w + tab * v1.w;
        sta += taa + tab;
    }
    float4* sh0 = (float4*)sm;              // 4*64 float4
    float4* sh1 = ((float4*)sm) + 256;      // 4*64 float4
    float* sW = sm + 2048;                  // 4
    sh0[wv * 64 + lane] = a0;
    sh1[wv * 64 + lane] = a1;
    if (lane == 0) sW[wv] = sta;
    __syncthreads();
    float* xbt = xt + b * ND;
    if (t < 64) {
        float4 s0 = sh0[t], s1 = sh0[64 + t], s2 = sh0[128 + t], s3 = sh0[192 + t];
        atomicAdd(&xbt[4 * t + 0], s0.x + s1.x + s2.x + s3.x);
        atomicAdd(&xbt[4 * t + 1], s0.y + s1.y + s2.y + s3.y);
        atomicAdd(&xbt[4 * t + 2], s0.z + s1.z + s2.z + s3.z);
        atomicAdd(&xbt[4 * t + 3], s0.w + s1.w + s2.w + s3.w);
    } else if (t < 128) {
        int l = t - 64;
        float4 s0 = sh1[l], s1 = sh1[64 + l], s2 = sh1[128 + l], s3 = sh1[192 + l];
        atomicAdd(&xbt[256 + 4 * l + 0], s0.x + s1.x + s2.x + s3.x);
        atomicAdd(&xbt[256 + 4 * l + 1], s0.y + s1.y + s2.y + s3.y);
        atomicAdd(&xbt[256 + 4 * l + 2], s0.z + s1.z + s2.z + s3.z);
        atomicAdd(&xbt[256 + 4 * l + 3], s0.w + s1.w + s2.w + s3.w);
    } else if (t == 128) {
        atomicAdd(&st[b], sW[0] + sW[1] + sW[2] + sW[3]);
    }
}

// ---- P6: out[b,f] = Wv[f,:].xt[b,:] + bv[f]*st[b], 8 f per block ----------
__device__ void d_out(int blk, const float* __restrict__ xt,
                      const float* __restrict__ st,
                      const float* __restrict__ Wv, const float* __restrict__ bv,
                      float* __restrict__ out) {
    const int b = blk >> 6;
    const int t = threadIdx.x;
    const int wv = t >> 6;
    const int lane = t & 63;
    const int f = (blk & 63) * 8 + wv * 2;
    const float4* xt4 = (const float4*)(xt + b * ND);
    const float4 xa = xt4[lane];
    const float4 xc = xt4[64 + lane];
    const float stb = st[b];
    const float4* w0p = (const float4*)(Wv + (size_t)f * ND);
    const float4* w1p = (const float4*)(Wv + (size_t)(f + 1) * ND);
    float p0 = dot4(xa, w0p[lane]) + dot4(xc, w0p[64 + lane]);
    float p1 = dot4(xa, w1p[lane]) + dot4(xc, w1p[64 + lane]);
#pragma unroll
    for (int m = 1; m < 64; m <<= 1) {
        p0 += __shfl_xor(p0, m, 64);
        p1 += __shfl_xor(p1, m, 64);
    }
    if (lane == 0) {
        out[b * NFF + f]     = p0 + bv[f] * stb;
        out[b * NFF + f + 1] = p1 + bv[f + 1] * stb;
    }
}

// ---- Mono kernel: 6 phases, 5 slot barriers, one launch -------------------
__global__ void __launch_bounds__(256, 8)
k_mono(const float* __restrict__ x, const float* __restrict__ Wq,
       const float* __restrict__ bq, const float* __restrict__ Wk,
       const float* __restrict__ bk, const float* __restrict__ Wv,
       const float* __restrict__ bv, const float* __restrict__ Wt,
       const float* __restrict__ bt, float* __restrict__ out,
       float* __restrict__ ws) {
    __shared__ __align__(16) float sm[2052];
    float* xwp = ws + OFF_XWP;
    float* xw  = ws + OFF_XW;
    float* kwS = ws + OFF_KWS;
    float* wqs = ws + OFF_WQS;
    float* cb2 = ws + OFF_CB2;
    float* xt  = ws + OFF_XT;
    float* st  = ws + OFF_ST;
    float* sw  = ws + OFF_SW;
    unsigned* slots   = (unsigned*)(ws + OFF_SLOT);
    unsigned* release = (unsigned*)(ws + OFF_REL);
    const int blk = blockIdx.x;

    d_pass1(blk, x, Wt, xwp, xt, st, sm);
    grid_barrier(1u, slots, release);
    if (blk < 64) d_xwred(blk, xwp, Wt, xw, sw);
    grid_barrier(2u, slots, release);
    d_kw(blk, xw, Wk, bk, sw, kwS);
    grid_barrier(3u, slots, release);
    if (blk < 64) d_wqs(blk, kwS, Wq, bq, bt, wqs, cb2, sm);
    grid_barrier(4u, slots, release);
    d_pass2(blk, x, wqs, cb2, xt, st, sm);
    grid_barrier(5u, slots, release);
    d_out(blk, xt, st, Wv, bv, out);
}

extern "C" void kernel_launch(void* const* d_in, const int* in_sizes, int n_in,
                              void* d_out, int out_size, void* d_ws, size_t ws_size,
                              hipStream_t stream) {
    const float* x  = (const float*)d_in[0];
    const float* Wq = (const float*)d_in[1];
    const float* bq = (const float*)d_in[2];
    const float* Wk = (const float*)d_in[3];
    const float* bk = (const float*)d_in[4];
    const float* Wv = (const float*)d_in[5];
    const float* bv = (const float*)d_in[6];
    const float* Wt = (const float*)d_in[7];
    const float* bt = (const float*)d_in[8];
    float* out = (float*)d_out;
    float* ws = (float*)d_ws;

    // Zero arrival slots + release word (workspace is poisoned per iteration).
    hipMemsetAsync(ws + OFF_SLOT, 0, 8704, stream);
    k_mono<<<GRID, 256, 0, stream>>>(x, Wq, bq, Wk, bk, Wv, bv, Wt, bt, out, ws);
}

// Round 4
// 347.827 us; speedup vs baseline: 4.4543x; 2.3486x over previous
//
#include <hip/hip_runtime.h>

// Problem constants
#define NB 32
#define NS 2048
#define ND 512
#define NFF 512
#define SCALE 0.044194173824159216f
#define PARTS 32            // blocks per batch
#define ROWSB 64            // rows per block
#define GRID (NB * PARTS)   // 1024

// Workspace float offsets. [0, ZERO_FLOATS) is zeroed by one hipMemsetAsync.
#define OFF_XW  0           // 16384 floats (atomic accum, pass 1)
#define OFF_XT  16384       // 16384 floats (atomic accum, pass 2)
#define OFF_ST  32768       // 32 floats    (atomic accum)
#define OFF_D1  32800       // 32 u32 done counters (k_front)
#define OFF_D2  32832       // 32 u32 done counters (k_back)
#define ZERO_FLOATS 32864
#define OFF_WQS 32864       // 16384 floats (k_front epilogue -> k_back)
#define OFF_CB2 49248       // 32 floats

__device__ __forceinline__ float dot4(float4 a, float4 b) {
    return a.x * b.x + a.y * b.y + a.z * b.z + a.w * b.w;
}

__device__ __forceinline__ float wave_reduce(float p) {
#pragma unroll
    for (int m = 1; m < 64; m <<= 1) p += __shfl_xor(p, m, 64);
    return p;
}

__device__ __forceinline__ void reduce2(float& p0, float& p1) {
#pragma unroll
    for (int m = 1; m < 64; m <<= 1) {
        p0 += __shfl_xor(p0, m, 64);
        p1 += __shfl_xor(p1, m, 64);
    }
}

__device__ __forceinline__ void reduce4(float& p0, float& p1, float& p2, float& p3) {
#pragma unroll
    for (int m = 1; m < 64; m <<= 1) {
        p0 += __shfl_xor(p0, m, 64);
        p1 += __shfl_xor(p1, m, 64);
        p2 += __shfl_xor(p2, m, 64);
        p3 += __shfl_xor(p3, m, 64);
    }
}

// Cache-bypassing load (sc0 sc1): reads the coherence point, where all
// device-scope atomics landed. No L2 invalidate needed.
__device__ __forceinline__ float coh_loadf(const float* p) {
    unsigned u = __hip_atomic_load((unsigned*)p, __ATOMIC_RELAXED,
                                   __HIP_MEMORY_SCOPE_AGENT);
    return __uint_as_float(u);
}

// ---- k_front: pass 1 (xw accum) + last-arriver middle chain ---------------
// Per block: 64 rows of batch b -> atomicAdd partial xw[b,:]. The 32nd
// arriver per batch reads xw coherently and computes kwS (LDS), wqs, cb2.
__global__ void __launch_bounds__(256, 2)
k_front(const float* __restrict__ x, const float* __restrict__ Wt,
        const float* __restrict__ Wk, const float* __restrict__ bk,
        const float* __restrict__ Wq, const float* __restrict__ bq,
        const float* __restrict__ bt, float* __restrict__ ws) {
    float* xw  = ws + OFF_XW;
    float* wqs = ws + OFF_WQS;
    float* cb2 = ws + OFF_CB2;
    unsigned* done = (unsigned*)(ws + OFF_D1);
    const int blk = blockIdx.x;
    const int b = blk >> 5;
    const int part = blk & 31;
    const int s0 = part * ROWSB;
    const int t = threadIdx.x;
    const int col = t & 127;
    const int half = t >> 7;

    __shared__ __align__(16) float4 red[128];   // pass1 reduce; reused as sxw
    __shared__ float skw[NFF];
    __shared__ float sred[4];
    __shared__ int lastflag;

    // stream 64 rows, weight by Wt[s], accumulate 512-wide partial
    const float4* xb = (const float4*)(x + (size_t)b * NS * ND);
    float4 acc = make_float4(0.f, 0.f, 0.f, 0.f);
#pragma unroll 8
    for (int i = 0; i < 32; i++) {
        int s = s0 + half + 2 * i;
        float w = Wt[s];
        float4 v = xb[(size_t)s * 128 + col];
        acc.x += w * v.x; acc.y += w * v.y; acc.z += w * v.z; acc.w += w * v.w;
    }
    if (half == 1) red[col] = acc;
    __syncthreads();
    if (half == 0) {
        float4 o = red[col];
        float* dst = xw + b * ND + col * 4;
        atomicAdd(dst + 0, o.x + acc.x);
        atomicAdd(dst + 1, o.y + acc.y);
        atomicAdd(dst + 2, o.z + acc.z);
        atomicAdd(dst + 3, o.w + acc.w);
    }
    // all this block's atomics performed at the coherence point
    asm volatile("s_waitcnt vmcnt(0)" ::: "memory");
    __syncthreads();
    if (t == 0) {
        unsigned old = __hip_atomic_fetch_add(&done[b], 1u, __ATOMIC_RELAXED,
                                              __HIP_MEMORY_SCOPE_AGENT);
        lastflag = (old == PARTS - 1);
    }
    __syncthreads();
    if (!lastflag) return;

    // ---- unique last block for batch b: middle GEMV chain ----
    float* sxw = (float*)red;   // 512 floats (pass1 use of `red` is done)
    sxw[t]       = coh_loadf(xw + b * ND + t);
    sxw[256 + t] = coh_loadf(xw + b * ND + 256 + t);
    {   // sw = sum(Wt)
        float a = 0.f;
#pragma unroll
        for (int i = 0; i < 8; i++) a += Wt[t + 256 * i];
        a = wave_reduce(a);
        if ((t & 63) == 0) sred[t >> 6] = a;
    }
    __syncthreads();
    const float sw = sred[0] + sred[1] + sred[2] + sred[3];
    const int wv = t >> 6;
    const int lane = t & 63;
    const float4* xa4 = (const float4*)sxw;
    const float4 xa = xa4[lane];
    const float4 xc = xa4[64 + lane];
    // kwS[f] = SCALE*(Wk[f,:].xw + bk[f]*sw), 128 f per wave, ILP-4
    for (int j = 0; j < 128; j += 4) {
        const int f = wv * 128 + j;
        const float4* r0 = (const float4*)(Wk + (size_t)f * ND);
        const float4* r1 = (const float4*)(Wk + (size_t)(f + 1) * ND);
        const float4* r2 = (const float4*)(Wk + (size_t)(f + 2) * ND);
        const float4* r3 = (const float4*)(Wk + (size_t)(f + 3) * ND);
        float p0 = dot4(xa, r0[lane]) + dot4(xc, r0[64 + lane]);
        float p1 = dot4(xa, r1[lane]) + dot4(xc, r1[64 + lane]);
        float p2 = dot4(xa, r2[lane]) + dot4(xc, r2[64 + lane]);
        float p3 = dot4(xa, r3[lane]) + dot4(xc, r3[64 + lane]);
        reduce4(p0, p1, p2, p3);
        if (lane == 0) {
            skw[f]     = SCALE * (p0 + bk[f]     * sw);
            skw[f + 1] = SCALE * (p1 + bk[f + 1] * sw);
            skw[f + 2] = SCALE * (p2 + bk[f + 2] * sw);
            skw[f + 3] = SCALE * (p3 + bk[f + 3] * sw);
        }
    }
    __syncthreads();
    // wqs[d] = sum_f skw[f]*Wq[f,d]  (coalesced over d, kernel-end flush
    // publishes these normal stores to k_back)
    {
        const float* wp = Wq + t;
        float a0 = 0.f, a1 = 0.f, b0 = 0.f, b1 = 0.f;
#pragma unroll 4
        for (int f = 0; f < NFF; f += 2) {
            float k0 = skw[f], k1 = skw[f + 1];
            const float* r0 = wp + (size_t)f * ND;
            const float* r1 = wp + (size_t)(f + 1) * ND;
            a0 += k0 * r0[0];   a1 += k0 * r0[256];
            b0 += k1 * r1[0];   b1 += k1 * r1[256];
        }
        wqs[b * ND + t]       = a0 + b0;
        wqs[b * ND + 256 + t] = a1 + b1;
    }
    // cb2[b] = skw.bq + bt
    {
        float v = skw[t] * bq[t] + skw[256 + t] * bq[256 + t];
        v = wave_reduce(v);
        __syncthreads();           // sred reuse after sw reads
        if (lane == 0) sred[wv] = v;
        __syncthreads();
        if (t == 0) cb2[b] = sred[0] + sred[1] + sred[2] + sred[3] + bt[0];
    }
}

// ---- k_back: pass 2 (ta -> xt/st accum) + last-arriver output GEMV --------
__global__ void __launch_bounds__(256, 2)
k_back(const float* __restrict__ x, const float* __restrict__ Wv,
       const float* __restrict__ bv, float* __restrict__ ws,
       float* __restrict__ out) {
    float* wqs = ws + OFF_WQS;
    float* cb2 = ws + OFF_CB2;
    float* xt  = ws + OFF_XT;
    float* st  = ws + OFF_ST;
    unsigned* done = (unsigned*)(ws + OFF_D2);
    const int blk = blockIdx.x;
    const int b = blk >> 5;
    const int part = blk & 31;
    const int s0 = part * ROWSB;
    const int t = threadIdx.x;
    const int wv = t >> 6;
    const int lane = t & 63;

    __shared__ __align__(16) float4 sh0[4][64];  // reused as sxt
    __shared__ __align__(16) float4 sh1[4][64];
    __shared__ float sW[4];
    __shared__ float sstb;
    __shared__ int lastflag;

    const float4* xb = (const float4*)(x + (size_t)b * NS * ND);
    const float4* wq4 = (const float4*)(wqs + b * ND);
    const float4 w0 = wq4[lane];
    const float4 w1 = wq4[64 + lane];
    const float c = cb2[b];
    float4 a0 = make_float4(0.f, 0.f, 0.f, 0.f);
    float4 a1 = make_float4(0.f, 0.f, 0.f, 0.f);
    float sta = 0.f;
#pragma unroll
    for (int g = 0; g < 8; g++) {
        int s = s0 + wv * 16 + 2 * g;
        float4 u0 = xb[(size_t)s * 128 + lane];
        float4 u1 = xb[(size_t)s * 128 + 64 + lane];
        float4 v0 = xb[(size_t)(s + 1) * 128 + lane];
        float4 v1 = xb[(size_t)(s + 1) * 128 + 64 + lane];
        float pa = dot4(u0, w0) + dot4(u1, w1);
        float pb = dot4(v0, w0) + dot4(v1, w1);
        reduce2(pa, pb);
        float taa = pa + c;
        float tab = pb + c;
        a0.x += taa * u0.x + tab * v0.x; a0.y += taa * u0.y + tab * v0.y;
        a0.z += taa * u0.z + tab * v0.z; a0.w += taa * u0.w + tab * v0.w;
        a1.x += taa * u1.x + tab * v1.x; a1.y += taa * u1.y + tab * v1.y;
        a1.z += taa * u1.z + tab * v1.z; a1.w += taa * u1.w + tab * v1.w;
        sta += taa + tab;
    }
    sh0[wv][lane] = a0;
    sh1[wv][lane] = a1;
    if (lane == 0) sW[wv] = sta;
    __syncthreads();
    float* xbt = xt + b * ND;
    if (t < 64) {
        float4 q0 = sh0[0][t], q1 = sh0[1][t], q2 = sh0[2][t], q3 = sh0[3][t];
        atomicAdd(&xbt[4 * t + 0], q0.x + q1.x + q2.x + q3.x);
        atomicAdd(&xbt[4 * t + 1], q0.y + q1.y + q2.y + q3.y);
        atomicAdd(&xbt[4 * t + 2], q0.z + q1.z + q2.z + q3.z);
        atomicAdd(&xbt[4 * t + 3], q0.w + q1.w + q2.w + q3.w);
    } else if (t < 128) {
        int l = t - 64;
        float4 q0 = sh1[0][l], q1 = sh1[1][l], q2 = sh1[2][l], q3 = sh1[3][l];
        atomicAdd(&xbt[256 + 4 * l + 0], q0.x + q1.x + q2.x + q3.x);
        atomicAdd(&xbt[256 + 4 * l + 1], q0.y + q1.y + q2.y + q3.y);
        atomicAdd(&xbt[256 + 4 * l + 2], q0.z + q1.z + q2.z + q3.z);
        atomicAdd(&xbt[256 + 4 * l + 3], q0.w + q1.w + q2.w + q3.w);
    } else if (t == 128) {
        atomicAdd(&st[b], sW[0] + sW[1] + sW[2] + sW[3]);
    }
    asm volatile("s_waitcnt vmcnt(0)" ::: "memory");
    __syncthreads();
    if (t == 0) {
        unsigned old = __hip_atomic_fetch_add(&done[b], 1u, __ATOMIC_RELAXED,
                                              __HIP_MEMORY_SCOPE_AGENT);
        lastflag = (old == PARTS - 1);
    }
    __syncthreads();
    if (!lastflag) return;

    // ---- unique last block for batch b: out[b,f] = Wv[f,:].xt + bv[f]*st --
    float* sxt = (float*)sh0;   // 512 floats
    sxt[t]       = coh_loadf(xt + b * ND + t);
    sxt[256 + t] = coh_loadf(xt + b * ND + 256 + t);
    if (t == 0) sstb = coh_loadf(st + b);
    __syncthreads();
    const float4* xa4 = (const float4*)sxt;
    const float4 xa = xa4[lane];
    const float4 xc = xa4[64 + lane];
    const float stb = sstb;
    for (int j = 0; j < 128; j += 4) {
        const int f = wv * 128 + j;
        const float4* r0 = (const float4*)(Wv + (size_t)f * ND);
        const float4* r1 = (const float4*)(Wv + (size_t)(f + 1) * ND);
        const float4* r2 = (const float4*)(Wv + (size_t)(f + 2) * ND);
        const float4* r3 = (const float4*)(Wv + (size_t)(f + 3) * ND);
        float p0 = dot4(xa, r0[lane]) + dot4(xc, r0[64 + lane]);
        float p1 = dot4(xa, r1[lane]) + dot4(xc, r1[64 + lane]);
        float p2 = dot4(xa, r2[lane]) + dot4(xc, r2[64 + lane]);
        float p3 = dot4(xa, r3[lane]) + dot4(xc, r3[64 + lane]);
        reduce4(p0, p1, p2, p3);
        if (lane == 0) {
            out[b * NFF + f]     = p0 + bv[f]     * stb;
            out[b * NFF + f + 1] = p1 + bv[f + 1] * stb;
            out[b * NFF + f + 2] = p2 + bv[f + 2] * stb;
            out[b * NFF + f + 3] = p3 + bv[f + 3] * stb;
        }
    }
}

extern "C" void kernel_launch(void* const* d_in, const int* in_sizes, int n_in,
                              void* d_out, int out_size, void* d_ws, size_t ws_size,
                              hipStream_t stream) {
    const float* x  = (const float*)d_in[0];
    const float* Wq = (const float*)d_in[1];
    const float* bq = (const float*)d_in[2];
    const float* Wk = (const float*)d_in[3];
    const float* bk = (const float*)d_in[4];
    const float* Wv = (const float*)d_in[5];
    const float* bv = (const float*)d_in[6];
    const float* Wt = (const float*)d_in[7];
    const float* bt = (const float*)d_in[8];
    float* out = (float*)d_out;
    float* ws = (float*)d_ws;

    // zero accumulators + done counters (workspace is poisoned per iteration)
    hipMemsetAsync(ws, 0, ZERO_FLOATS * sizeof(float), stream);
    k_front<<<GRID, 256, 0, stream>>>(x, Wt, Wk, bk, Wq, bq, bt, ws);
    k_back<<<GRID, 256, 0, stream>>>(x, Wv, bv, ws, out);
}